// Round 1
// 748.182 us; speedup vs baseline: 1.2071x; 1.2071x over previous
//
#include <hip/hip_runtime.h>
#include <hip/hip_bf16.h>
#include <stdint.h>

typedef unsigned int uint_t;
typedef unsigned short ushort_t;

#define NN 100000
#define EE 1600000
#define CC 25000
#define DINTER 144
#define NW 19531250u      // bitmap words: 625e6 bits / 32
#define NBLK 2385         // bitmap blocks: ceil(NW / 8192)

// ---- ws layout in 32-bit words ----
#define W_M1B      0u         // u16 [131*128] bf16 m1 = 8384 words (region [0,100000) was unused)
#define W_CNT      100000u    // u32 [25000]
#define W_OFFS     125000u    // u32 [25008] (needs 25001)
#define W_CURSOR   150008u    // u32 [25000]
#define W_NEWPOS   175008u    // f32 [25000*4]
#define W_M1F      275008u    // f32 [131*128] row-major [j][o] (now unused)
#define W_AGGB     291776u    // bf16[25000*132] = 1,650,000 words
#define W_SSRC     1941776u   // u32 [1600000]  (edge ids, cluster-sorted)
#define W_BITMAP   3541776u   // u32 [19531250]
#define W_BSUMS    23073026u  // u32 [2385]
#define W_BOFFS    23075411u  // u32 [2386]
#define WS_WORDS   23077797u

// ---- out layout in FLOAT32 elements (total 11,300,000) ----
#define O_XNEW  0u
#define O_POS   3200000u
#define O_EI    3275000u
#define O_ATTR  6475000u
#define O_BATCH 11275000u
// x_bf16 staging: first 6.4M words of the O_EI region (re-zeroed before bitmap_emit)

static __device__ __forceinline__ uint_t f2bf(float f) {
    union { float f; uint_t i; } v; v.f = f;
    uint_t x = v.i;
    return (x + 0x7fffu + ((x >> 16) & 1u)) >> 16;  // RNE
}
static __device__ __forceinline__ float bf2f(ushort_t u) {
    union { uint_t i; float f; } v; v.i = ((uint_t)u) << 16; return v.f;
}

// K0: pack x (f32) -> bf16x2 words into the output-staging region.
__global__ void xpack(const float4* __restrict__ x4, uint2* __restrict__ xb2) {
    int i = blockIdx.x * 256 + threadIdx.x;
    if (i >= NN * 32) return;            // 12.8M floats / 4
    float4 v = x4[i];
    uint2 r;
    r.x = f2bf(v.x) | (f2bf(v.y) << 16);
    r.y = f2bf(v.z) | (f2bf(v.w) << 16);
    xb2[i] = r;
}

// K1: M1[j][o] = sum_f Wrow_j[f] * Wg[f][o], emitted directly as bf16.
__global__ void build_m1f(const float* __restrict__ Wconv,
                          const float* __restrict__ Wedge,
                          const float* __restrict__ Wg,
                          ushort_t* __restrict__ m1b) {
    int j = blockIdx.x;   // 0..130
    int o = threadIdx.x;  // 0..127
    const float* wrow = (j < 128) ? (Wconv + j * DINTER + 16)
                                  : (Wedge + (j - 128) * DINTER + 16);
    float acc = 0.f;
    for (int f = 0; f < 128; ++f)
        acc += wrow[f] * Wg[f * 128 + o];
    m1b[j * 128 + o] = (ushort_t)f2bf(acc);
}

// K2a: per-edge: count dst-clusters + set enc bit.
__global__ void edge_pass1(const int* __restrict__ ei,
                           uint_t* __restrict__ cnt, uint_t* __restrict__ bitmap) {
    int e = blockIdx.x * 256 + threadIdx.x;
    if (e >= EE) return;
    uint_t src = (uint_t)ei[e];
    uint_t dst = (uint_t)ei[EE + e];
    uint_t c = dst >> 2;
    atomicAdd(&cnt[c], 1u);
    uint_t enc = (src >> 2) * 25000u + c;
    atomicOr(&bitmap[enc >> 5], 1u << (enc & 31u));
}

// Single-block exclusive scan. out[0..n] (out[n]=total), optional copy out2[0..n-1].
__global__ void scan_small(const uint_t* __restrict__ in, uint_t* __restrict__ out,
                           uint_t* __restrict__ out2, int n) {
    __shared__ uint_t part[256];
    int tid = threadIdx.x;
    int per = (n + 255) >> 8;
    int lo = tid * per;
    int hi = lo + per; if (hi > n) hi = n;
    if (lo > n) lo = n;
    uint_t s = 0;
    for (int i = lo; i < hi; ++i) s += in[i];
    part[tid] = s;
    __syncthreads();
    for (int off = 1; off < 256; off <<= 1) {
        uint_t v = (tid >= off) ? part[tid - off] : 0u;
        __syncthreads();
        part[tid] += v;
        __syncthreads();
    }
    uint_t run = part[tid] - s;
    for (int i = lo; i < hi; ++i) {
        out[i] = run;
        if (out2) out2[i] = run;
        run += in[i];
    }
    if (tid == 255) out[n] = run;
}

// K2c: place edges into cluster-sorted order (store EDGE ID).
__global__ void edge_place(const int* __restrict__ ei, uint_t* __restrict__ cursor,
                           uint_t* __restrict__ sedge) {
    int e = blockIdx.x * 256 + threadIdx.x;
    if (e >= EE) return;
    uint_t dst = (uint_t)ei[EE + e];
    uint_t p = atomicAdd(&cursor[dst >> 2], 1u);
    sedge[p] = (uint_t)e;
}

// K3: per cluster: new_pos (f32 ws + f32 out), new_batch.
__global__ void cluster_pass(const float* __restrict__ pos, const int* __restrict__ batch,
                             float* __restrict__ newpos, float* __restrict__ out) {
    int c = blockIdx.x * 256 + threadIdx.x;
    if (c >= CC) return;
    float px = 0.f, py = 0.f, pz = 0.f;
    for (int j = 0; j < 4; ++j) {
        int n = c * 4 + j;
        px += pos[n * 3 + 0];
        py += pos[n * 3 + 1];
        pz += pos[n * 3 + 2];
    }
    px *= 0.25f; py *= 0.25f; pz *= 0.25f;
    newpos[c * 4 + 0] = px; newpos[c * 4 + 1] = py; newpos[c * 4 + 2] = pz;
    out[O_POS + c * 3 + 0] = px;
    out[O_POS + c * 3 + 1] = py;
    out[O_POS + c * 3 + 2] = pz;
    int b = batch[c * 4];
    b = max(b, batch[c * 4 + 1]);
    b = max(b, batch[c * 4 + 2]);
    b = max(b, batch[c * 4 + 3]);
    out[O_BATCH + c] = (float)b;
}

// K2d: one wave per cluster. Lanes cooperatively load 64 edge ids + srcs (coalesced /
// 64-wide MLP), broadcast srcs via shfl, gather bf16 x rows (256 B each). Each lane
// privately accumulates its own edges' edge_attr; wave-reduced at the end. No atomics.
__global__ void cluster_reduce(const uint_t* __restrict__ offs, const uint_t* __restrict__ sedge,
                               const int* __restrict__ ei, const float* __restrict__ ea,
                               const uint_t* __restrict__ xb, ushort_t* __restrict__ aggb) {
    int wid = (blockIdx.x * 256 + threadIdx.x) >> 6;
    int lane = threadIdx.x & 63;
    if (wid >= CC) return;
    uint_t start = offs[wid], end = offs[wid + 1];
    float a0 = 0.f, a1 = 0.f, t0 = 0.f, t1 = 0.f, t2 = 0.f;
    for (uint_t base = start; base < end; base += 64u) {
        uint_t idx = base + (uint_t)lane;
        int nm = (int)min(64u, end - base);
        int s = 0;
        if (idx < end) {
            uint_t e = sedge[idx];
            s = ei[e];
            t0 += ea[e * 3 + 0];
            t1 += ea[e * 3 + 1];
            t2 += ea[e * 3 + 2];
        }
        if (nm == 64) {
            #pragma unroll 8
            for (int j = 0; j < 64; ++j) {
                uint_t sj = (uint_t)__shfl(s, j, 64);
                uint_t w = xb[(size_t)sj * 64 + lane];
                a0 += bf2f((ushort_t)(w & 0xffffu));
                a1 += bf2f((ushort_t)(w >> 16));
            }
        } else {
            for (int j = 0; j < nm; ++j) {
                uint_t sj = (uint_t)__shfl(s, j, 64);
                uint_t w = xb[(size_t)sj * 64 + lane];
                a0 += bf2f((ushort_t)(w & 0xffffu));
                a1 += bf2f((ushort_t)(w >> 16));
            }
        }
    }
    uint_t v = f2bf(a0) | (f2bf(a1) << 16);
    *(uint_t*)(aggb + (size_t)wid * 132 + 2 * lane) = v;
    for (int off = 32; off; off >>= 1) {
        t0 += __shfl_down(t0, off, 64);
        t1 += __shfl_down(t1, off, 64);
        t2 += __shfl_down(t2, off, 64);
    }
    if (lane == 0) {
        uint_t w0 = f2bf(t0) | (f2bf(t1) << 16);
        uint_t w1 = f2bf(t2);   // slot 131 = 0
        *(uint_t*)(aggb + (size_t)wid * 132 + 128) = w0;
        *(uint_t*)(aggb + (size_t)wid * 132 + 130) = w1;
    }
}

// K4: x_new[c][o] = 0.25 * sum_{j<131} aggb[c][j] * M1[j][o].
// Restructured for occupancy: 782 blocks x 32 clusters (was 256 x 98 -> 1 block/CU,
// 11.5% occupancy, 200 us). Per iteration: stage 8 cluster rows TRANSPOSED into LDS
// (srowT[j][cg]); each thread owns (4 clusters x 1 output): inner loop per j is
// 1 ds_read_u16 (m1, 2-way=free) + 1 cvt + 1 broadcast ds_read_b128 + 4 FMA.
#define GEMM_CPB 32   // clusters per block = 4 iterations of 8
__global__ void gemm_tiled(const ushort_t* __restrict__ aggb, const ushort_t* __restrict__ m1b,
                           float* __restrict__ out) {
    __shared__ ushort_t m1s[131 * 128];            // 33.5 KB bf16
    __shared__ __align__(16) float srowT[132][8];  // 4.2 KB, [j][cluster-in-group]
    int tid = threadIdx.x;
    // stage m1 (already bf16 in ws) via coalesced u32 copy
    {
        const uint_t* m1w = (const uint_t*)m1b;
        uint_t* m1sw = (uint_t*)m1s;
        for (int i = tid; i < 131 * 64; i += 256) m1sw[i] = m1w[i];
    }
    int o = tid & 127, half = tid >> 7;
    int c0b = blockIdx.x * GEMM_CPB;
    const uint_t* aggw = (const uint_t*)aggb;      // row = 66 u32 words
    for (int it = 0; it < GEMM_CPB / 8; ++it) {
        int c0 = c0b + it * 8;
        __syncthreads();   // previous-iteration readers done before overwrite
        // stage 8 cluster rows transposed: 8*66 = 528 u32 words
        for (int i = tid; i < 528; i += 256) {
            int cg = i / 66, rem = i - cg * 66;
            int c = c0 + cg;
            uint_t w = (c < CC) ? aggw[(size_t)c * 66 + rem] : 0u;
            srowT[rem * 2][cg]     = bf2f((ushort_t)(w & 0xffffu));
            srowT[rem * 2 + 1][cg] = bf2f((ushort_t)(w >> 16));
        }
        __syncthreads();   // also covers m1s staging on it==0
        float acc0 = 0.f, acc1 = 0.f, acc2 = 0.f, acc3 = 0.f;
        #pragma unroll 4
        for (int j = 0; j < 131; ++j) {
            float m = bf2f(m1s[j * 128 + o]);
            float4 s = *(const float4*)&srowT[j][half * 4];  // broadcast within wave
            acc0 += s.x * m;
            acc1 += s.y * m;
            acc2 += s.z * m;
            acc3 += s.w * m;
        }
        int cb = c0 + half * 4;
        if (cb + 0 < CC) out[O_XNEW + (size_t)(cb + 0) * 128 + o] = 0.25f * acc0;
        if (cb + 1 < CC) out[O_XNEW + (size_t)(cb + 1) * 128 + o] = 0.25f * acc1;
        if (cb + 2 < CC) out[O_XNEW + (size_t)(cb + 2) * 128 + o] = 0.25f * acc2;
        if (cb + 3 < CC) out[O_XNEW + (size_t)(cb + 3) * 128 + o] = 0.25f * acc3;
    }
}

// K6a: per-block popcount of 8192 bitmap words — coalesced uint4 reads.
__global__ void bitmap_count(const uint_t* __restrict__ bitmap, uint_t* __restrict__ bsums) {
    __shared__ uint_t sh[256];
    int tid = threadIdx.x;
    uint_t B = (uint_t)blockIdx.x * 8192u;
    uint_t s = 0;
    for (int j = 0; j < 8; ++j) {
        uint_t w = B + (uint_t)j * 1024u + (uint_t)tid * 4u;
        if (w + 3u < NW) {
            uint4 v = *(const uint4*)(bitmap + w);
            s += __popc(v.x) + __popc(v.y) + __popc(v.z) + __popc(v.w);
        } else {
            for (int k = 0; k < 4; ++k)
                if (w + (uint_t)k < NW) s += __popc(bitmap[w + k]);
        }
    }
    sh[tid] = s;
    __syncthreads();
    for (int off = 128; off; off >>= 1) {
        if (tid < off) sh[tid] += sh[tid + off];
        __syncthreads();
    }
    if (tid == 0) bsums[blockIdx.x] = sh[0];
}

// K6c: coalesced-load bitmap into padded LDS, then per-thread 32-consecutive-word emit.
__global__ void bitmap_emit(const uint_t* __restrict__ bitmap, const uint_t* __restrict__ boffs,
                            const float* __restrict__ newpos, float* __restrict__ out) {
    __shared__ uint_t lds[256 * 33];
    __shared__ uint_t sh[256];
    int tid = threadIdx.x;
    uint_t B = (uint_t)blockIdx.x * 8192u;
    for (int j = 0; j < 8; ++j) {
        uint_t g = (uint_t)j * 1024u + (uint_t)tid * 4u;
        uint_t w = B + g;
        uint4 v;
        if (w + 3u < NW) {
            v = *(const uint4*)(bitmap + w);
        } else {
            v.x = (w < NW) ? bitmap[w] : 0u;
            v.y = (w + 1u < NW) ? bitmap[w + 1u] : 0u;
            v.z = (w + 2u < NW) ? bitmap[w + 2u] : 0u;
            v.w = (w + 3u < NW) ? bitmap[w + 3u] : 0u;
        }
        uint_t row = g >> 5, col = g & 31u;
        uint_t a = row * 33u + col;
        lds[a] = v.x; lds[a + 1u] = v.y; lds[a + 2u] = v.z; lds[a + 3u] = v.w;
    }
    __syncthreads();
    uint_t mine = 0;
    for (int j = 0; j < 32; ++j) mine += __popc(lds[tid * 33 + j]);
    sh[tid] = mine;
    __syncthreads();
    for (int off = 1; off < 256; off <<= 1) {
        uint_t v = (tid >= off) ? sh[tid - off] : 0u;
        __syncthreads();
        sh[tid] += v;
        __syncthreads();
    }
    uint_t rank = boffs[blockIdx.x] + sh[tid] - mine;
    uint_t wbase = B + (uint_t)tid * 32u;
    for (int j = 0; j < 32; ++j) {
        uint_t bits = lds[tid * 33 + j];
        uint_t w = wbase + (uint_t)j;
        while (bits) {
            int b = __builtin_ctz(bits);
            bits &= bits - 1u;
            uint_t enc = w * 32u + (uint_t)b;
            uint_t u = enc / 25000u;
            uint_t v = enc - u * 25000u;
            out[O_EI + rank] = (float)u;
            out[O_EI + EE + rank] = (float)v;
            out[O_ATTR + (size_t)rank * 3 + 0] = newpos[v * 4 + 0] - newpos[u * 4 + 0];
            out[O_ATTR + (size_t)rank * 3 + 1] = newpos[v * 4 + 1] - newpos[u * 4 + 1];
            out[O_ATTR + (size_t)rank * 3 + 2] = newpos[v * 4 + 2] - newpos[u * 4 + 2];
            rank++;
        }
    }
}

extern "C" void kernel_launch(void* const* d_in, const int* in_sizes, int n_in,
                              void* d_out, int out_size, void* d_ws, size_t ws_size,
                              hipStream_t stream) {
    const float* x     = (const float*)d_in[0];
    const float* pos   = (const float*)d_in[1];
    const int*   ei    = (const int*)d_in[2];
    const float* ea    = (const float*)d_in[3];
    const int*   batch = (const int*)d_in[4];
    const float* Wconv = (const float*)d_in[5];
    const float* Wedge = (const float*)d_in[6];
    // d_in[7] = D_bloom: dead (bloom_pos never reaches an output)
    const float* Wg    = (const float*)d_in[8];
    // d_in[9] = W_gattr: contribution cancels exactly within each cluster

    float*  out = (float*)d_out;
    uint_t* ws  = (uint_t*)d_ws;

    if (ws_size < (size_t)WS_WORDS * 4) return;

    ushort_t* m1b    = (ushort_t*)(ws + W_M1B);
    uint_t*   cnt    = ws + W_CNT;
    uint_t*   offs   = ws + W_OFFS;
    uint_t*   cursor = ws + W_CURSOR;
    float*    newpos = (float*)(ws + W_NEWPOS);
    ushort_t* aggb   = (ushort_t*)(ws + W_AGGB);
    uint_t*   sedge  = ws + W_SSRC;
    uint_t*   bitmap = ws + W_BITMAP;
    uint_t*   bsums  = ws + W_BSUMS;
    uint_t*   boffs  = ws + W_BOFFS;
    uint_t*   xb     = (uint_t*)(out + O_EI);   // 6.4M-word bf16-x staging in out region

    hipMemsetAsync(cnt, 0, (size_t)25000 * 4, stream);
    hipMemsetAsync(bitmap, 0, (size_t)NW * 4, stream);

    xpack<<<dim3(12500), dim3(256), 0, stream>>>((const float4*)x, (uint2*)xb);
    build_m1f<<<dim3(131), dim3(128), 0, stream>>>(Wconv, Wedge, Wg, m1b);
    edge_pass1<<<dim3(6250), dim3(256), 0, stream>>>(ei, cnt, bitmap);
    scan_small<<<dim3(1), dim3(256), 0, stream>>>(cnt, offs, cursor, CC);
    edge_place<<<dim3(6250), dim3(256), 0, stream>>>(ei, cursor, sedge);
    cluster_pass<<<dim3(98), dim3(256), 0, stream>>>(pos, batch, newpos, out);
    cluster_reduce<<<dim3(6250), dim3(256), 0, stream>>>(offs, sedge, ei, ea, xb, aggb);
    gemm_tiled<<<dim3((CC + GEMM_CPB - 1) / GEMM_CPB), dim3(256), 0, stream>>>(aggb, m1b, out);
    // x_bf16 staging no longer needed: zero the EI/ATTR region (incl. padding tail)
    hipMemsetAsync((char*)d_out + (size_t)O_EI * 4, 0, (size_t)(3200000 + 4800000) * 4, stream);
    bitmap_count<<<dim3(NBLK), dim3(256), 0, stream>>>(bitmap, bsums);
    scan_small<<<dim3(1), dim3(256), 0, stream>>>(bsums, boffs, (uint_t*)0, NBLK);
    bitmap_emit<<<dim3(NBLK), dim3(256), 0, stream>>>(bitmap, boffs, newpos, out);
}

// Round 3
// 659.301 us; speedup vs baseline: 1.3699x; 1.1348x over previous
//
#include <hip/hip_runtime.h>
#include <hip/hip_bf16.h>
#include <stdint.h>

typedef unsigned int uint_t;
typedef unsigned short ushort_t;

#define NN 100000
#define EE 1600000
#define CC 25000
#define DINTER 144
#define NBKT 196          // coarse buckets: cluster >> 7 (25000/128 -> 196)

// ---- ws layout in 32-bit words ----
#define W_M1B      0u         // u16 [131*128] bf16 m1 = 8384 words
#define W_OFFS     125000u    // u32 [25001]
#define W_NEWPOS   175008u    // f32 [25000*4]
#define W_AGGB     291776u    // bf16[25000*132] = 1,650,000 words
#define W_SSRC     1941776u   // u32 [1600000]  (edge ids, cluster-sorted)
#define W_PKA      3541776u   // u32 [1600000]  bucketed (c_local<<21|e)
#define W_PKC      5141776u   // u32 [1600000]  bucketed (u<<15|v)
#define W_BHA      6741776u   // u32 [196]
#define W_BHC      6741972u   // u32 [196]
#define W_BBA      6742168u   // u32 [197]
#define W_BBC      6742365u   // u32 [197]
#define W_BCURA    6742562u   // u32 [196]
#define W_BCURC    6742758u   // u32 [196]
#define W_BCNTC    6742954u   // u32 [196*8 = 1568]
#define W_EBASE    6744522u   // u32 [1569]
#define WS_WORDS   6746091u

// ---- out layout in FLOAT32 elements (total 11,300,000) ----
#define O_XNEW  0u
#define O_POS   3200000u
#define O_EI    3275000u
#define O_ATTR  6475000u
#define O_BATCH 11275000u
// x_bf16 staging: first 6.4M words of the O_EI region (re-zeroed before enc_emit)

static __device__ __forceinline__ uint_t f2bf(float f) {
    union { float f; uint_t i; } v; v.f = f;
    uint_t x = v.i;
    return (x + 0x7fffu + ((x >> 16) & 1u)) >> 16;  // RNE
}
static __device__ __forceinline__ float bf2f(ushort_t u) {
    union { uint_t i; float f; } v; v.i = ((uint_t)u) << 16; return v.f;
}

// K0: pack x (f32) -> bf16x2 words into the output-staging region.
__global__ void xpack(const float4* __restrict__ x4, uint2* __restrict__ xb2) {
    int i = blockIdx.x * 256 + threadIdx.x;
    if (i >= NN * 32) return;            // 12.8M floats / 4
    float4 v = x4[i];
    uint2 r;
    r.x = f2bf(v.x) | (f2bf(v.y) << 16);
    r.y = f2bf(v.z) | (f2bf(v.w) << 16);
    xb2[i] = r;
}

// K1: M1[j][o] = sum_f Wrow_j[f] * Wg[f][o], emitted directly as bf16.
__global__ void build_m1f(const float* __restrict__ Wconv,
                          const float* __restrict__ Wedge,
                          const float* __restrict__ Wg,
                          ushort_t* __restrict__ m1b) {
    int j = blockIdx.x;   // 0..130
    int o = threadIdx.x;  // 0..127
    const float* wrow = (j < 128) ? (Wconv + j * DINTER + 16)
                                  : (Wedge + (j - 128) * DINTER + 16);
    float acc = 0.f;
    for (int f = 0; f < 128; ++f)
        acc += wrow[f] * Wg[f * 128 + o];
    m1b[j * 128 + o] = (ushort_t)f2bf(acc);
}

// K2a: fused coarse histograms (LDS-aggregated, ~50K global atomics total).
// bhA: by dst cluster >> 7 (edge sort).  bhC: by src cluster >> 7 (enc dedupe).
__global__ void edge_hist(const int* __restrict__ ei,
                          uint_t* __restrict__ bhA, uint_t* __restrict__ bhC) {
    __shared__ uint_t hA[NBKT], hC[NBKT];
    int tid = threadIdx.x;
    for (int i = tid; i < NBKT; i += 256) { hA[i] = 0; hC[i] = 0; }
    __syncthreads();
    for (int e = blockIdx.x * 256 + tid; e < EE; e += 256 * 256) {
        uint_t u = ((uint_t)ei[e]) >> 2;
        uint_t v = ((uint_t)ei[EE + e]) >> 2;
        atomicAdd(&hA[v >> 7], 1u);
        atomicAdd(&hC[u >> 7], 1u);
    }
    __syncthreads();
    for (int i = tid; i < NBKT; i += 256) {
        if (hA[i]) atomicAdd(&bhA[i], hA[i]);
        if (hC[i]) atomicAdd(&bhC[i], hC[i]);
    }
}

// Single-block exclusive scan. out[0..n] (out[n]=total), optional copy out2[0..n-1].
__global__ void scan_small(const uint_t* __restrict__ in, uint_t* __restrict__ out,
                           uint_t* __restrict__ out2, int n) {
    __shared__ uint_t part[256];
    int tid = threadIdx.x;
    int per = (n + 255) >> 8;
    int lo = tid * per;
    int hi = lo + per; if (hi > n) hi = n;
    if (lo > n) lo = n;
    uint_t s = 0;
    for (int i = lo; i < hi; ++i) s += in[i];
    part[tid] = s;
    __syncthreads();
    for (int off = 1; off < 256; off <<= 1) {
        uint_t v = (tid >= off) ? part[tid - off] : 0u;
        __syncthreads();
        part[tid] += v;
        __syncthreads();
    }
    uint_t run = part[tid] - s;
    for (int i = lo; i < hi; ++i) {
        out[i] = run;
        if (out2) out2[i] = run;
        run += in[i];
    }
    if (tid == 255) out[n] = run;
}

#define TPB 4096
// K2b: tile-reordered bucket scatter by dst cluster (payload packs c_local|edge id).
// Per block: 196 reservation atomics; writes are grouped ~84B runs (vs 4B random).
__global__ void bucket_place_A(const int* __restrict__ ei, uint_t* __restrict__ bcur,
                               uint_t* __restrict__ pkA) {
    __shared__ uint_t pk[TPB];
    __shared__ unsigned char bk[TPB];
    __shared__ uint_t gpk[TPB];
    __shared__ unsigned char gbk[TPB];
    __shared__ uint_t hist[NBKT], lbase[NBKT], gbase[NBKT], cur[NBKT];
    __shared__ uint_t part[256];
    int tid = threadIdx.x;
    int t0 = blockIdx.x * TPB;
    int nt = EE - t0; if (nt > TPB) nt = TPB;
    for (int i = tid; i < NBKT; i += 256) { hist[i] = 0; cur[i] = 0; }
    __syncthreads();
    for (int i = tid; i < nt; i += 256) {
        int e = t0 + i;
        uint_t c = ((uint_t)ei[EE + e]) >> 2;
        uint_t b = c >> 7;
        pk[i] = ((c & 127u) << 21) | (uint_t)e;
        bk[i] = (unsigned char)b;
        atomicAdd(&hist[b], 1u);
    }
    __syncthreads();
    uint_t h = (tid < NBKT) ? hist[tid] : 0u;
    if (tid < NBKT) gbase[tid] = atomicAdd(&bcur[tid], h);
    part[tid] = h;
    __syncthreads();
    for (int off = 1; off < 256; off <<= 1) {
        uint_t v = (tid >= off) ? part[tid - off] : 0u;
        __syncthreads();
        part[tid] += v;
        __syncthreads();
    }
    if (tid < NBKT) lbase[tid] = part[tid] - h;
    __syncthreads();
    for (int i = tid; i < nt; i += 256) {
        uint_t b = bk[i];
        uint_t r = lbase[b] + atomicAdd(&cur[b], 1u);
        gpk[r] = pk[i];
        gbk[r] = (unsigned char)b;
    }
    __syncthreads();
    for (int r = tid; r < nt; r += 256) {
        uint_t b = gbk[r];
        pkA[gbase[b] + ((uint_t)r - lbase[b])] = gpk[r];
    }
}

// K2b': same machinery keyed by src cluster; full key (u<<15)|v fits u32, bucket = pk>>22.
__global__ void bucket_place_C(const int* __restrict__ ei, uint_t* __restrict__ bcur,
                               uint_t* __restrict__ pkC) {
    __shared__ uint_t pk[TPB];
    __shared__ uint_t gpk[TPB];
    __shared__ uint_t hist[NBKT], lbase[NBKT], gbase[NBKT], cur[NBKT];
    __shared__ uint_t part[256];
    int tid = threadIdx.x;
    int t0 = blockIdx.x * TPB;
    int nt = EE - t0; if (nt > TPB) nt = TPB;
    for (int i = tid; i < NBKT; i += 256) { hist[i] = 0; cur[i] = 0; }
    __syncthreads();
    for (int i = tid; i < nt; i += 256) {
        int e = t0 + i;
        uint_t u = ((uint_t)ei[e]) >> 2;
        uint_t v = ((uint_t)ei[EE + e]) >> 2;
        uint_t w = (u << 15) | v;
        pk[i] = w;
        atomicAdd(&hist[w >> 22], 1u);
    }
    __syncthreads();
    uint_t h = (tid < NBKT) ? hist[tid] : 0u;
    if (tid < NBKT) gbase[tid] = atomicAdd(&bcur[tid], h);
    part[tid] = h;
    __syncthreads();
    for (int off = 1; off < 256; off <<= 1) {
        uint_t v = (tid >= off) ? part[tid - off] : 0u;
        __syncthreads();
        part[tid] += v;
        __syncthreads();
    }
    if (tid < NBKT) lbase[tid] = part[tid] - h;
    __syncthreads();
    for (int i = tid; i < nt; i += 256) {
        uint_t b = pk[i] >> 22;
        uint_t r = lbase[b] + atomicAdd(&cur[b], 1u);
        gpk[r] = pk[i];
    }
    __syncthreads();
    for (int r = tid; r < nt; r += 256) {
        uint_t b = gpk[r] >> 22;
        pkC[gbase[b] + ((uint_t)r - lbase[b])] = gpk[r];
    }
}

// K2c: one block per bucket: 128-bin LDS counting sort -> sedge (edge ids) + offs[c].
// Bucket region is single-block-owned -> L2 accumulates full lines -> ~1x writeback.
__global__ void bucket_sort_A(const uint_t* __restrict__ bbA, const uint_t* __restrict__ pkA,
                              uint_t* __restrict__ sedge, uint_t* __restrict__ offs) {
    __shared__ uint_t hist[128], base2[128], cur[128];
    __shared__ uint_t part[256];
    int tid = threadIdx.x;
    int bk = blockIdx.x;
    uint_t s = bbA[bk], epos = bbA[bk + 1];
    int n = (int)(epos - s);
    if (tid < 128) { hist[tid] = 0; cur[tid] = 0; }
    __syncthreads();
    for (int i = tid; i < n; i += 256) atomicAdd(&hist[pkA[s + i] >> 21], 1u);
    __syncthreads();
    uint_t h = (tid < 128) ? hist[tid] : 0u;
    part[tid] = h;
    __syncthreads();
    for (int off = 1; off < 256; off <<= 1) {
        uint_t v = (tid >= off) ? part[tid - off] : 0u;
        __syncthreads();
        part[tid] += v;
        __syncthreads();
    }
    if (tid < 128) {
        base2[tid] = part[tid] - h;
        int c = bk * 128 + tid;
        if (c < CC) offs[c] = s + base2[tid];
    }
    if (bk == 0 && tid == 0) offs[CC] = EE;
    __syncthreads();
    for (int i = tid; i < n; i += 256) {
        uint_t w = pkA[s + i];
        uint_t d = w >> 21;
        uint_t r = base2[d] + atomicAdd(&cur[d], 1u);
        sedge[s + r] = w & 0x1FFFFFu;
    }
}

// K3: per cluster: new_pos (f32 ws + f32 out), new_batch.
__global__ void cluster_pass(const float* __restrict__ pos, const int* __restrict__ batch,
                             float* __restrict__ newpos, float* __restrict__ out) {
    int c = blockIdx.x * 256 + threadIdx.x;
    if (c >= CC) return;
    float px = 0.f, py = 0.f, pz = 0.f;
    for (int j = 0; j < 4; ++j) {
        int n = c * 4 + j;
        px += pos[n * 3 + 0];
        py += pos[n * 3 + 1];
        pz += pos[n * 3 + 2];
    }
    px *= 0.25f; py *= 0.25f; pz *= 0.25f;
    newpos[c * 4 + 0] = px; newpos[c * 4 + 1] = py; newpos[c * 4 + 2] = pz;
    out[O_POS + c * 3 + 0] = px;
    out[O_POS + c * 3 + 1] = py;
    out[O_POS + c * 3 + 2] = pz;
    int b = batch[c * 4];
    b = max(b, batch[c * 4 + 1]);
    b = max(b, batch[c * 4 + 2]);
    b = max(b, batch[c * 4 + 3]);
    out[O_BATCH + c] = (float)b;
}

// K2d: one wave per cluster. Lanes cooperatively load 64 edge ids + srcs, broadcast
// srcs via shfl, gather bf16 x rows (256 B each). Private edge_attr accumulation.
__global__ void cluster_reduce(const uint_t* __restrict__ offs, const uint_t* __restrict__ sedge,
                               const int* __restrict__ ei, const float* __restrict__ ea,
                               const uint_t* __restrict__ xb, ushort_t* __restrict__ aggb) {
    int wid = (blockIdx.x * 256 + threadIdx.x) >> 6;
    int lane = threadIdx.x & 63;
    if (wid >= CC) return;
    uint_t start = offs[wid], end = offs[wid + 1];
    float a0 = 0.f, a1 = 0.f, t0 = 0.f, t1 = 0.f, t2 = 0.f;
    for (uint_t base = start; base < end; base += 64u) {
        uint_t idx = base + (uint_t)lane;
        int nm = (int)min(64u, end - base);
        int s = 0;
        if (idx < end) {
            uint_t e = sedge[idx];
            s = ei[e];
            t0 += ea[e * 3 + 0];
            t1 += ea[e * 3 + 1];
            t2 += ea[e * 3 + 2];
        }
        if (nm == 64) {
            #pragma unroll 8
            for (int j = 0; j < 64; ++j) {
                uint_t sj = (uint_t)__shfl(s, j, 64);
                uint_t w = xb[(size_t)sj * 64 + lane];
                a0 += bf2f((ushort_t)(w & 0xffffu));
                a1 += bf2f((ushort_t)(w >> 16));
            }
        } else {
            for (int j = 0; j < nm; ++j) {
                uint_t sj = (uint_t)__shfl(s, j, 64);
                uint_t w = xb[(size_t)sj * 64 + lane];
                a0 += bf2f((ushort_t)(w & 0xffffu));
                a1 += bf2f((ushort_t)(w >> 16));
            }
        }
    }
    uint_t v = f2bf(a0) | (f2bf(a1) << 16);
    *(uint_t*)(aggb + (size_t)wid * 132 + 2 * lane) = v;
    for (int off = 32; off; off >>= 1) {
        t0 += __shfl_down(t0, off, 64);
        t1 += __shfl_down(t1, off, 64);
        t2 += __shfl_down(t2, off, 64);
    }
    if (lane == 0) {
        uint_t w0 = f2bf(t0) | (f2bf(t1) << 16);
        uint_t w1 = f2bf(t2);   // slot 131 = 0
        *(uint_t*)(aggb + (size_t)wid * 132 + 128) = w0;
        *(uint_t*)(aggb + (size_t)wid * 132 + 130) = w1;
    }
}

// K4: x_new[c][o] = 0.25 * sum_{j<131} aggb[c][j] * M1[j][o].
#define GEMM_CPB 32   // clusters per block = 4 iterations of 8
__global__ void gemm_tiled(const ushort_t* __restrict__ aggb, const ushort_t* __restrict__ m1b,
                           float* __restrict__ out) {
    __shared__ ushort_t m1s[131 * 128];            // 33.5 KB bf16
    __shared__ __align__(16) float srowT[132][8];  // 4.2 KB, [j][cluster-in-group]
    int tid = threadIdx.x;
    {
        const uint_t* m1w = (const uint_t*)m1b;
        uint_t* m1sw = (uint_t*)m1s;
        for (int i = tid; i < 131 * 64; i += 256) m1sw[i] = m1w[i];
    }
    int o = tid & 127, half = tid >> 7;
    int c0b = blockIdx.x * GEMM_CPB;
    const uint_t* aggw = (const uint_t*)aggb;      // row = 66 u32 words
    for (int it = 0; it < GEMM_CPB / 8; ++it) {
        int c0 = c0b + it * 8;
        __syncthreads();   // previous-iteration readers done before overwrite
        for (int i = tid; i < 528; i += 256) {
            int cg = i / 66, rem = i - cg * 66;
            int c = c0 + cg;
            uint_t w = (c < CC) ? aggw[(size_t)c * 66 + rem] : 0u;
            srowT[rem * 2][cg]     = bf2f((ushort_t)(w & 0xffffu));
            srowT[rem * 2 + 1][cg] = bf2f((ushort_t)(w >> 16));
        }
        __syncthreads();   // also covers m1s staging on it==0
        float acc0 = 0.f, acc1 = 0.f, acc2 = 0.f, acc3 = 0.f;
        #pragma unroll 4
        for (int j = 0; j < 131; ++j) {
            float m = bf2f(m1s[j * 128 + o]);
            float4 s = *(const float4*)&srowT[j][half * 4];  // broadcast within wave
            acc0 += s.x * m;
            acc1 += s.y * m;
            acc2 += s.z * m;
            acc3 += s.w * m;
        }
        int cb = c0 + half * 4;
        if (cb + 0 < CC) out[O_XNEW + (size_t)(cb + 0) * 128 + o] = 0.25f * acc0;
        if (cb + 1 < CC) out[O_XNEW + (size_t)(cb + 1) * 128 + o] = 0.25f * acc1;
        if (cb + 2 < CC) out[O_XNEW + (size_t)(cb + 2) * 128 + o] = 0.25f * acc2;
        if (cb + 3 < CC) out[O_XNEW + (size_t)(cb + 3) * 128 + o] = 0.25f * acc3;
    }
}

// K6a: per-bucket unique-(u,v) counts via LDS bitmap. 8 sub-rounds of 16 u-clusters
// (bitmap 16*25000 bits = 50 KB LDS). Replaces the 78 MB global bitmap entirely.
__global__ void enc_count(const uint_t* __restrict__ bbC, const uint_t* __restrict__ pkC,
                          uint_t* __restrict__ bcnt) {
    __shared__ uint_t bmp[12500];
    __shared__ uint_t red[256];
    int tid = threadIdx.x, bk = blockIdx.x;
    uint_t s = bbC[bk], epos = bbC[bk + 1];
    int n = (int)(epos - s);
    for (int sub = 0; sub < 8; ++sub) {
        for (int i = tid; i < 12500; i += 256) bmp[i] = 0;
        __syncthreads();
        for (int i = tid; i < n; i += 256) {
            uint_t w = pkC[s + i];
            if (((w >> 19) & 7u) == (uint_t)sub) {
                uint_t le = ((w >> 15) & 15u) * 25000u + (w & 32767u);
                atomicOr(&bmp[le >> 5], 1u << (le & 31u));
            }
        }
        __syncthreads();
        uint_t cnt = 0;
        for (int i = tid; i < 12500; i += 256) cnt += __popc(bmp[i]);
        red[tid] = cnt;
        __syncthreads();
        for (int off = 128; off; off >>= 1) {
            if (tid < off) red[tid] += red[tid + off];
            __syncthreads();
        }
        if (tid == 0) bcnt[bk * 8 + sub] = red[0];
        __syncthreads();
    }
}

// K6b: rebuild per-sub LDS bitmap, rank via block scan, emit new edges + attrs in
// ascending enc order (bucket asc, sub asc, word asc, bit asc == (u,v) lex asc).
__global__ void enc_emit(const uint_t* __restrict__ bbC, const uint_t* __restrict__ pkC,
                         const uint_t* __restrict__ ebase, const float* __restrict__ newpos,
                         float* __restrict__ out) {
    __shared__ uint_t bmp[12500];
    __shared__ uint_t sh[256];
    int tid = threadIdx.x, bk = blockIdx.x;
    uint_t s = bbC[bk], epos = bbC[bk + 1];
    int n = (int)(epos - s);
    int lo = tid * 49, hi = lo + 49; if (hi > 12500) hi = 12500;
    for (int sub = 0; sub < 8; ++sub) {
        for (int i = tid; i < 12500; i += 256) bmp[i] = 0;
        __syncthreads();
        for (int i = tid; i < n; i += 256) {
            uint_t w = pkC[s + i];
            if (((w >> 19) & 7u) == (uint_t)sub) {
                uint_t le = ((w >> 15) & 15u) * 25000u + (w & 32767u);
                atomicOr(&bmp[le >> 5], 1u << (le & 31u));
            }
        }
        __syncthreads();
        uint_t mine = 0;
        for (int i = lo; i < hi; ++i) mine += __popc(bmp[i]);
        sh[tid] = mine;
        __syncthreads();
        for (int off = 1; off < 256; off <<= 1) {
            uint_t v = (tid >= off) ? sh[tid - off] : 0u;
            __syncthreads();
            sh[tid] += v;
            __syncthreads();
        }
        uint_t rank = ebase[bk * 8 + sub] + sh[tid] - mine;
        uint_t ubase = (uint_t)bk * 128u + (uint_t)sub * 16u;
        for (int i = lo; i < hi; ++i) {
            uint_t bits = bmp[i];
            while (bits) {
                int b = __builtin_ctz(bits);
                bits &= bits - 1u;
                uint_t le = (uint_t)i * 32u + (uint_t)b;
                uint_t uo = le / 25000u;
                uint_t v = le - uo * 25000u;
                uint_t u = ubase + uo;
                out[O_EI + rank] = (float)u;
                out[O_EI + EE + rank] = (float)v;
                out[O_ATTR + (size_t)rank * 3 + 0] = newpos[v * 4 + 0] - newpos[u * 4 + 0];
                out[O_ATTR + (size_t)rank * 3 + 1] = newpos[v * 4 + 1] - newpos[u * 4 + 1];
                out[O_ATTR + (size_t)rank * 3 + 2] = newpos[v * 4 + 2] - newpos[u * 4 + 2];
                rank++;
            }
        }
        __syncthreads();
    }
}

extern "C" void kernel_launch(void* const* d_in, const int* in_sizes, int n_in,
                              void* d_out, int out_size, void* d_ws, size_t ws_size,
                              hipStream_t stream) {
    const float* x     = (const float*)d_in[0];
    const float* pos   = (const float*)d_in[1];
    const int*   ei    = (const int*)d_in[2];
    const float* ea    = (const float*)d_in[3];
    const int*   batch = (const int*)d_in[4];
    const float* Wconv = (const float*)d_in[5];
    const float* Wedge = (const float*)d_in[6];
    // d_in[7] = D_bloom: dead (bloom_pos never reaches an output)
    const float* Wg    = (const float*)d_in[8];
    // d_in[9] = W_gattr: contribution cancels exactly within each cluster

    float*  out = (float*)d_out;
    uint_t* ws  = (uint_t*)d_ws;

    if (ws_size < (size_t)WS_WORDS * 4) return;

    ushort_t* m1b    = (ushort_t*)(ws + W_M1B);
    uint_t*   offs   = ws + W_OFFS;
    float*    newpos = (float*)(ws + W_NEWPOS);
    ushort_t* aggb   = (ushort_t*)(ws + W_AGGB);
    uint_t*   sedge  = ws + W_SSRC;
    uint_t*   pkA    = ws + W_PKA;
    uint_t*   pkC    = ws + W_PKC;
    uint_t*   bhA    = ws + W_BHA;
    uint_t*   bhC    = ws + W_BHC;
    uint_t*   bbA    = ws + W_BBA;
    uint_t*   bbC    = ws + W_BBC;
    uint_t*   bcurA  = ws + W_BCURA;
    uint_t*   bcurC  = ws + W_BCURC;
    uint_t*   bcntC  = ws + W_BCNTC;
    uint_t*   ebase  = ws + W_EBASE;
    uint_t*   xb     = (uint_t*)(out + O_EI);   // 6.4M-word bf16-x staging in out region

    hipMemsetAsync(bhA, 0, (size_t)(2 * NBKT) * 4, stream);   // bhA + bhC contiguous

    xpack<<<dim3(12500), dim3(256), 0, stream>>>((const float4*)x, (uint2*)xb);
    build_m1f<<<dim3(131), dim3(128), 0, stream>>>(Wconv, Wedge, Wg, m1b);
    edge_hist<<<dim3(256), dim3(256), 0, stream>>>(ei, bhA, bhC);
    scan_small<<<dim3(1), dim3(256), 0, stream>>>(bhA, bbA, bcurA, NBKT);
    scan_small<<<dim3(1), dim3(256), 0, stream>>>(bhC, bbC, bcurC, NBKT);
    bucket_place_A<<<dim3((EE + TPB - 1) / TPB), dim3(256), 0, stream>>>(ei, bcurA, pkA);
    bucket_place_C<<<dim3((EE + TPB - 1) / TPB), dim3(256), 0, stream>>>(ei, bcurC, pkC);
    bucket_sort_A<<<dim3(NBKT), dim3(256), 0, stream>>>(bbA, pkA, sedge, offs);
    cluster_pass<<<dim3(98), dim3(256), 0, stream>>>(pos, batch, newpos, out);
    cluster_reduce<<<dim3(6250), dim3(256), 0, stream>>>(offs, sedge, ei, ea, xb, aggb);
    gemm_tiled<<<dim3((CC + GEMM_CPB - 1) / GEMM_CPB), dim3(256), 0, stream>>>(aggb, m1b, out);
    // x_bf16 staging no longer needed: zero the EI/ATTR region (incl. padding tail)
    hipMemsetAsync((char*)d_out + (size_t)O_EI * 4, 0, (size_t)(3200000 + 4800000) * 4, stream);
    enc_count<<<dim3(NBKT), dim3(256), 0, stream>>>(bbC, pkC, bcntC);
    scan_small<<<dim3(1), dim3(256), 0, stream>>>(bcntC, ebase, (uint_t*)0, NBKT * 8);
    enc_emit<<<dim3(NBKT), dim3(256), 0, stream>>>(bbC, pkC, ebase, newpos, out);
}

// Round 4
// 547.331 us; speedup vs baseline: 1.6501x; 1.2046x over previous
//
#include <hip/hip_runtime.h>
#include <hip/hip_bf16.h>
#include <stdint.h>

typedef unsigned int uint_t;
typedef unsigned short ushort_t;

#define NN 100000
#define EE 1600000
#define CC 25000
#define DINTER 144
#define NBKT 196          // coarse buckets: cluster >> 7 (25000/128 -> 196)

// ---- ws layout in 32-bit words ----
#define W_M1B      0u         // u16 [131*128] bf16 m1 = 8384 words
#define W_OFFS     125000u    // u32 [25001]
#define W_NEWPOS   175008u    // f32 [25000*4]
#define W_AGGB     291776u    // bf16[25000*132] = 1,650,000 words
#define W_SSRC     1941776u   // u32 [1600000]  (edge ids, cluster-sorted)
#define W_PKA      3541776u   // u32 [1600000]  bucketed (c_local<<21|e)
#define W_PKC      5141776u   // u32 [1600000]  bucketed (u<<15|v)
#define W_BHA      6741776u   // u32 [196]
#define W_BHC      6741972u   // u32 [196]
#define W_BBA      6742168u   // u32 [197]
#define W_BBC      6742365u   // u32 [197]
#define W_BCURA    6742562u   // u32 [196]
#define W_BCURC    6742758u   // u32 [196]
#define W_BCNTC    6742954u   // u32 [196*8 = 1568]
#define W_EBASE    6744522u   // u32 [1569]
#define WS_WORDS   6746091u

// ---- out layout in FLOAT32 elements (total 11,300,000) ----
#define O_XNEW  0u
#define O_POS   3200000u
#define O_EI    3275000u
#define O_ATTR  6475000u
#define O_BATCH 11275000u
// x_bf16 staging: first 6.4M words of the O_EI region (re-zeroed before enc_emit)

static __device__ __forceinline__ uint_t f2bf(float f) {
    union { float f; uint_t i; } v; v.f = f;
    uint_t x = v.i;
    return (x + 0x7fffu + ((x >> 16) & 1u)) >> 16;  // RNE
}
static __device__ __forceinline__ float bf2f(ushort_t u) {
    union { uint_t i; float f; } v; v.i = ((uint_t)u) << 16; return v.f;
}

// K0: pack x (f32) -> bf16x2 words into the output-staging region.
__global__ void xpack(const float4* __restrict__ x4, uint2* __restrict__ xb2) {
    int i = blockIdx.x * 256 + threadIdx.x;
    if (i >= NN * 32) return;            // 12.8M floats / 4
    float4 v = x4[i];
    uint2 r;
    r.x = f2bf(v.x) | (f2bf(v.y) << 16);
    r.y = f2bf(v.z) | (f2bf(v.w) << 16);
    xb2[i] = r;
}

// K1: M1[j][o] = sum_f Wrow_j[f] * Wg[f][o], emitted directly as bf16.
__global__ void build_m1f(const float* __restrict__ Wconv,
                          const float* __restrict__ Wedge,
                          const float* __restrict__ Wg,
                          ushort_t* __restrict__ m1b) {
    int j = blockIdx.x;   // 0..130
    int o = threadIdx.x;  // 0..127
    const float* wrow = (j < 128) ? (Wconv + j * DINTER + 16)
                                  : (Wedge + (j - 128) * DINTER + 16);
    float acc = 0.f;
    for (int f = 0; f < 128; ++f)
        acc += wrow[f] * Wg[f * 128 + o];
    m1b[j * 128 + o] = (ushort_t)f2bf(acc);
}

// K2a: fused coarse histograms (LDS-aggregated, ~50K global atomics total).
// bhA: by dst cluster >> 7 (edge sort).  bhC: by src cluster >> 7 (enc dedupe).
__global__ void edge_hist(const int* __restrict__ ei,
                          uint_t* __restrict__ bhA, uint_t* __restrict__ bhC) {
    __shared__ uint_t hA[NBKT], hC[NBKT];
    int tid = threadIdx.x;
    for (int i = tid; i < NBKT; i += 256) { hA[i] = 0; hC[i] = 0; }
    __syncthreads();
    for (int e = blockIdx.x * 256 + tid; e < EE; e += 256 * 256) {
        uint_t u = ((uint_t)ei[e]) >> 2;
        uint_t v = ((uint_t)ei[EE + e]) >> 2;
        atomicAdd(&hA[v >> 7], 1u);
        atomicAdd(&hC[u >> 7], 1u);
    }
    __syncthreads();
    for (int i = tid; i < NBKT; i += 256) {
        if (hA[i]) atomicAdd(&bhA[i], hA[i]);
        if (hC[i]) atomicAdd(&bhC[i], hC[i]);
    }
}

// Single-block exclusive scan. out[0..n] (out[n]=total), optional copy out2[0..n-1].
__global__ void scan_small(const uint_t* __restrict__ in, uint_t* __restrict__ out,
                           uint_t* __restrict__ out2, int n) {
    __shared__ uint_t part[256];
    int tid = threadIdx.x;
    int per = (n + 255) >> 8;
    int lo = tid * per;
    int hi = lo + per; if (hi > n) hi = n;
    if (lo > n) lo = n;
    uint_t s = 0;
    for (int i = lo; i < hi; ++i) s += in[i];
    part[tid] = s;
    __syncthreads();
    for (int off = 1; off < 256; off <<= 1) {
        uint_t v = (tid >= off) ? part[tid - off] : 0u;
        __syncthreads();
        part[tid] += v;
        __syncthreads();
    }
    uint_t run = part[tid] - s;
    for (int i = lo; i < hi; ++i) {
        out[i] = run;
        if (out2) out2[i] = run;
        run += in[i];
    }
    if (tid == 255) out[n] = run;
}

#define TPB 4096
// K2b: tile-reordered bucket scatter by dst cluster (payload packs c_local|edge id).
// Per block: 196 reservation atomics; writes are grouped ~84B runs (vs 4B random).
__global__ void bucket_place_A(const int* __restrict__ ei, uint_t* __restrict__ bcur,
                               uint_t* __restrict__ pkA) {
    __shared__ uint_t pk[TPB];
    __shared__ unsigned char bk[TPB];
    __shared__ uint_t gpk[TPB];
    __shared__ unsigned char gbk[TPB];
    __shared__ uint_t hist[NBKT], lbase[NBKT], gbase[NBKT], cur[NBKT];
    __shared__ uint_t part[256];
    int tid = threadIdx.x;
    int t0 = blockIdx.x * TPB;
    int nt = EE - t0; if (nt > TPB) nt = TPB;
    for (int i = tid; i < NBKT; i += 256) { hist[i] = 0; cur[i] = 0; }
    __syncthreads();
    for (int i = tid; i < nt; i += 256) {
        int e = t0 + i;
        uint_t c = ((uint_t)ei[EE + e]) >> 2;
        uint_t b = c >> 7;
        pk[i] = ((c & 127u) << 21) | (uint_t)e;
        bk[i] = (unsigned char)b;
        atomicAdd(&hist[b], 1u);
    }
    __syncthreads();
    uint_t h = (tid < NBKT) ? hist[tid] : 0u;
    if (tid < NBKT) gbase[tid] = atomicAdd(&bcur[tid], h);
    part[tid] = h;
    __syncthreads();
    for (int off = 1; off < 256; off <<= 1) {
        uint_t v = (tid >= off) ? part[tid - off] : 0u;
        __syncthreads();
        part[tid] += v;
        __syncthreads();
    }
    if (tid < NBKT) lbase[tid] = part[tid] - h;
    __syncthreads();
    for (int i = tid; i < nt; i += 256) {
        uint_t b = bk[i];
        uint_t r = lbase[b] + atomicAdd(&cur[b], 1u);
        gpk[r] = pk[i];
        gbk[r] = (unsigned char)b;
    }
    __syncthreads();
    for (int r = tid; r < nt; r += 256) {
        uint_t b = gbk[r];
        pkA[gbase[b] + ((uint_t)r - lbase[b])] = gpk[r];
    }
}

// K2b': same machinery keyed by src cluster; full key (u<<15)|v fits u32, bucket = pk>>22.
__global__ void bucket_place_C(const int* __restrict__ ei, uint_t* __restrict__ bcur,
                               uint_t* __restrict__ pkC) {
    __shared__ uint_t pk[TPB];
    __shared__ uint_t gpk[TPB];
    __shared__ uint_t hist[NBKT], lbase[NBKT], gbase[NBKT], cur[NBKT];
    __shared__ uint_t part[256];
    int tid = threadIdx.x;
    int t0 = blockIdx.x * TPB;
    int nt = EE - t0; if (nt > TPB) nt = TPB;
    for (int i = tid; i < NBKT; i += 256) { hist[i] = 0; cur[i] = 0; }
    __syncthreads();
    for (int i = tid; i < nt; i += 256) {
        int e = t0 + i;
        uint_t u = ((uint_t)ei[e]) >> 2;
        uint_t v = ((uint_t)ei[EE + e]) >> 2;
        uint_t w = (u << 15) | v;
        pk[i] = w;
        atomicAdd(&hist[w >> 22], 1u);
    }
    __syncthreads();
    uint_t h = (tid < NBKT) ? hist[tid] : 0u;
    if (tid < NBKT) gbase[tid] = atomicAdd(&bcur[tid], h);
    part[tid] = h;
    __syncthreads();
    for (int off = 1; off < 256; off <<= 1) {
        uint_t v = (tid >= off) ? part[tid - off] : 0u;
        __syncthreads();
        part[tid] += v;
        __syncthreads();
    }
    if (tid < NBKT) lbase[tid] = part[tid] - h;
    __syncthreads();
    for (int i = tid; i < nt; i += 256) {
        uint_t b = pk[i] >> 22;
        uint_t r = lbase[b] + atomicAdd(&cur[b], 1u);
        gpk[r] = pk[i];
    }
    __syncthreads();
    for (int r = tid; r < nt; r += 256) {
        uint_t b = gpk[r] >> 22;
        pkC[gbase[b] + ((uint_t)r - lbase[b])] = gpk[r];
    }
}

// K2c: one block per bucket: 128-bin LDS counting sort -> sedge (edge ids) + offs[c].
// Bucket region is single-block-owned -> L2 accumulates full lines -> ~1x writeback.
__global__ void bucket_sort_A(const uint_t* __restrict__ bbA, const uint_t* __restrict__ pkA,
                              uint_t* __restrict__ sedge, uint_t* __restrict__ offs) {
    __shared__ uint_t hist[128], base2[128], cur[128];
    __shared__ uint_t part[256];
    int tid = threadIdx.x;
    int bk = blockIdx.x;
    uint_t s = bbA[bk], epos = bbA[bk + 1];
    int n = (int)(epos - s);
    if (tid < 128) { hist[tid] = 0; cur[tid] = 0; }
    __syncthreads();
    for (int i = tid; i < n; i += 256) atomicAdd(&hist[pkA[s + i] >> 21], 1u);
    __syncthreads();
    uint_t h = (tid < 128) ? hist[tid] : 0u;
    part[tid] = h;
    __syncthreads();
    for (int off = 1; off < 256; off <<= 1) {
        uint_t v = (tid >= off) ? part[tid - off] : 0u;
        __syncthreads();
        part[tid] += v;
        __syncthreads();
    }
    if (tid < 128) {
        base2[tid] = part[tid] - h;
        int c = bk * 128 + tid;
        if (c < CC) offs[c] = s + base2[tid];
    }
    if (bk == 0 && tid == 0) offs[CC] = EE;
    __syncthreads();
    for (int i = tid; i < n; i += 256) {
        uint_t w = pkA[s + i];
        uint_t d = w >> 21;
        uint_t r = base2[d] + atomicAdd(&cur[d], 1u);
        sedge[s + r] = w & 0x1FFFFFu;
    }
}

// K3: per cluster: new_pos (f32 ws + f32 out), new_batch.
__global__ void cluster_pass(const float* __restrict__ pos, const int* __restrict__ batch,
                             float* __restrict__ newpos, float* __restrict__ out) {
    int c = blockIdx.x * 256 + threadIdx.x;
    if (c >= CC) return;
    float px = 0.f, py = 0.f, pz = 0.f;
    for (int j = 0; j < 4; ++j) {
        int n = c * 4 + j;
        px += pos[n * 3 + 0];
        py += pos[n * 3 + 1];
        pz += pos[n * 3 + 2];
    }
    px *= 0.25f; py *= 0.25f; pz *= 0.25f;
    newpos[c * 4 + 0] = px; newpos[c * 4 + 1] = py; newpos[c * 4 + 2] = pz;
    out[O_POS + c * 3 + 0] = px;
    out[O_POS + c * 3 + 1] = py;
    out[O_POS + c * 3 + 2] = pz;
    int b = batch[c * 4];
    b = max(b, batch[c * 4 + 1]);
    b = max(b, batch[c * 4 + 2]);
    b = max(b, batch[c * 4 + 3]);
    out[O_BATCH + c] = (float)b;
}

// K2d: one wave per cluster. Lanes cooperatively load 64 edge ids + srcs, broadcast
// srcs via shfl, gather bf16 x rows (256 B each). Private edge_attr accumulation.
__global__ void cluster_reduce(const uint_t* __restrict__ offs, const uint_t* __restrict__ sedge,
                               const int* __restrict__ ei, const float* __restrict__ ea,
                               const uint_t* __restrict__ xb, ushort_t* __restrict__ aggb) {
    int wid = (blockIdx.x * 256 + threadIdx.x) >> 6;
    int lane = threadIdx.x & 63;
    if (wid >= CC) return;
    uint_t start = offs[wid], end = offs[wid + 1];
    float a0 = 0.f, a1 = 0.f, t0 = 0.f, t1 = 0.f, t2 = 0.f;
    for (uint_t base = start; base < end; base += 64u) {
        uint_t idx = base + (uint_t)lane;
        int nm = (int)min(64u, end - base);
        int s = 0;
        if (idx < end) {
            uint_t e = sedge[idx];
            s = ei[e];
            t0 += ea[e * 3 + 0];
            t1 += ea[e * 3 + 1];
            t2 += ea[e * 3 + 2];
        }
        if (nm == 64) {
            #pragma unroll 8
            for (int j = 0; j < 64; ++j) {
                uint_t sj = (uint_t)__shfl(s, j, 64);
                uint_t w = xb[(size_t)sj * 64 + lane];
                a0 += bf2f((ushort_t)(w & 0xffffu));
                a1 += bf2f((ushort_t)(w >> 16));
            }
        } else {
            for (int j = 0; j < nm; ++j) {
                uint_t sj = (uint_t)__shfl(s, j, 64);
                uint_t w = xb[(size_t)sj * 64 + lane];
                a0 += bf2f((ushort_t)(w & 0xffffu));
                a1 += bf2f((ushort_t)(w >> 16));
            }
        }
    }
    uint_t v = f2bf(a0) | (f2bf(a1) << 16);
    *(uint_t*)(aggb + (size_t)wid * 132 + 2 * lane) = v;
    for (int off = 32; off; off >>= 1) {
        t0 += __shfl_down(t0, off, 64);
        t1 += __shfl_down(t1, off, 64);
        t2 += __shfl_down(t2, off, 64);
    }
    if (lane == 0) {
        uint_t w0 = f2bf(t0) | (f2bf(t1) << 16);
        uint_t w1 = f2bf(t2);   // slot 131 = 0
        *(uint_t*)(aggb + (size_t)wid * 132 + 128) = w0;
        *(uint_t*)(aggb + (size_t)wid * 132 + 130) = w1;
    }
}

// K4: x_new[c][o] = 0.25 * sum_{j<131} aggb[c][j] * M1[j][o].
#define GEMM_CPB 32   // clusters per block = 4 iterations of 8
__global__ void gemm_tiled(const ushort_t* __restrict__ aggb, const ushort_t* __restrict__ m1b,
                           float* __restrict__ out) {
    __shared__ ushort_t m1s[131 * 128];            // 33.5 KB bf16
    __shared__ __align__(16) float srowT[132][8];  // 4.2 KB, [j][cluster-in-group]
    int tid = threadIdx.x;
    {
        const uint_t* m1w = (const uint_t*)m1b;
        uint_t* m1sw = (uint_t*)m1s;
        for (int i = tid; i < 131 * 64; i += 256) m1sw[i] = m1w[i];
    }
    int o = tid & 127, half = tid >> 7;
    int c0b = blockIdx.x * GEMM_CPB;
    const uint_t* aggw = (const uint_t*)aggb;      // row = 66 u32 words
    for (int it = 0; it < GEMM_CPB / 8; ++it) {
        int c0 = c0b + it * 8;
        __syncthreads();   // previous-iteration readers done before overwrite
        for (int i = tid; i < 528; i += 256) {
            int cg = i / 66, rem = i - cg * 66;
            int c = c0 + cg;
            uint_t w = (c < CC) ? aggw[(size_t)c * 66 + rem] : 0u;
            srowT[rem * 2][cg]     = bf2f((ushort_t)(w & 0xffffu));
            srowT[rem * 2 + 1][cg] = bf2f((ushort_t)(w >> 16));
        }
        __syncthreads();   // also covers m1s staging on it==0
        float acc0 = 0.f, acc1 = 0.f, acc2 = 0.f, acc3 = 0.f;
        #pragma unroll 4
        for (int j = 0; j < 131; ++j) {
            float m = bf2f(m1s[j * 128 + o]);
            float4 s = *(const float4*)&srowT[j][half * 4];  // broadcast within wave
            acc0 += s.x * m;
            acc1 += s.y * m;
            acc2 += s.z * m;
            acc3 += s.w * m;
        }
        int cb = c0 + half * 4;
        if (cb + 0 < CC) out[O_XNEW + (size_t)(cb + 0) * 128 + o] = 0.25f * acc0;
        if (cb + 1 < CC) out[O_XNEW + (size_t)(cb + 1) * 128 + o] = 0.25f * acc1;
        if (cb + 2 < CC) out[O_XNEW + (size_t)(cb + 2) * 128 + o] = 0.25f * acc2;
        if (cb + 3 < CC) out[O_XNEW + (size_t)(cb + 3) * 128 + o] = 0.25f * acc3;
    }
}

// K6a: per-(bucket,sub) unique-(u,v) counts via 50 KB LDS bitmap (16 u-clusters x
// 25000 v bits). Grid = NBKT*8 — one block per sub-round (was 8 serial rounds in
// 196 blocks -> grid-starved at 8.7% occupancy).
__global__ void enc_count(const uint_t* __restrict__ bbC, const uint_t* __restrict__ pkC,
                          uint_t* __restrict__ bcnt) {
    __shared__ uint_t bmp[12500];
    __shared__ uint_t red[256];
    int tid = threadIdx.x;
    int bk = blockIdx.x >> 3;
    uint_t sub = (uint_t)(blockIdx.x & 7);
    uint_t s = bbC[bk], epos = bbC[bk + 1];
    int n = (int)(epos - s);
    for (int i = tid; i < 12500; i += 256) bmp[i] = 0;
    __syncthreads();
    for (int i = tid; i < n; i += 256) {
        uint_t w = pkC[s + i];
        if (((w >> 19) & 7u) == sub) {
            uint_t le = ((w >> 15) & 15u) * 25000u + (w & 32767u);
            atomicOr(&bmp[le >> 5], 1u << (le & 31u));
        }
    }
    __syncthreads();
    uint_t cnt = 0;
    for (int i = tid; i < 12500; i += 256) cnt += __popc(bmp[i]);
    red[tid] = cnt;
    __syncthreads();
    for (int off = 128; off; off >>= 1) {
        if (tid < off) red[tid] += red[tid + off];
        __syncthreads();
    }
    if (tid == 0) bcnt[blockIdx.x] = red[0];
}

// K6b: rebuild the (bucket,sub) LDS bitmap, rank via block scan, emit new edges +
// attrs in ascending enc order (bk asc, sub asc, word asc, bit asc == (u,v) lex asc).
__global__ void enc_emit(const uint_t* __restrict__ bbC, const uint_t* __restrict__ pkC,
                         const uint_t* __restrict__ ebase, const float* __restrict__ newpos,
                         float* __restrict__ out) {
    __shared__ uint_t bmp[12500];
    __shared__ uint_t sh[256];
    int tid = threadIdx.x;
    int bk = blockIdx.x >> 3;
    uint_t sub = (uint_t)(blockIdx.x & 7);
    uint_t s = bbC[bk], epos = bbC[bk + 1];
    int n = (int)(epos - s);
    int lo = tid * 49, hi = lo + 49; if (hi > 12500) hi = 12500;
    for (int i = tid; i < 12500; i += 256) bmp[i] = 0;
    __syncthreads();
    for (int i = tid; i < n; i += 256) {
        uint_t w = pkC[s + i];
        if (((w >> 19) & 7u) == sub) {
            uint_t le = ((w >> 15) & 15u) * 25000u + (w & 32767u);
            atomicOr(&bmp[le >> 5], 1u << (le & 31u));
        }
    }
    __syncthreads();
    uint_t mine = 0;
    for (int i = lo; i < hi; ++i) mine += __popc(bmp[i]);
    sh[tid] = mine;
    __syncthreads();
    for (int off = 1; off < 256; off <<= 1) {
        uint_t v = (tid >= off) ? sh[tid - off] : 0u;
        __syncthreads();
        sh[tid] += v;
        __syncthreads();
    }
    uint_t rank = ebase[blockIdx.x] + sh[tid] - mine;
    uint_t ubase = (uint_t)bk * 128u + sub * 16u;
    for (int i = lo; i < hi; ++i) {
        uint_t bits = bmp[i];
        while (bits) {
            int b = __builtin_ctz(bits);
            bits &= bits - 1u;
            uint_t le = (uint_t)i * 32u + (uint_t)b;
            uint_t uo = le / 25000u;
            uint_t v = le - uo * 25000u;
            uint_t u = ubase + uo;
            out[O_EI + rank] = (float)u;
            out[O_EI + EE + rank] = (float)v;
            out[O_ATTR + (size_t)rank * 3 + 0] = newpos[v * 4 + 0] - newpos[u * 4 + 0];
            out[O_ATTR + (size_t)rank * 3 + 1] = newpos[v * 4 + 1] - newpos[u * 4 + 1];
            out[O_ATTR + (size_t)rank * 3 + 2] = newpos[v * 4 + 2] - newpos[u * 4 + 2];
            rank++;
        }
    }
}

extern "C" void kernel_launch(void* const* d_in, const int* in_sizes, int n_in,
                              void* d_out, int out_size, void* d_ws, size_t ws_size,
                              hipStream_t stream) {
    const float* x     = (const float*)d_in[0];
    const float* pos   = (const float*)d_in[1];
    const int*   ei    = (const int*)d_in[2];
    const float* ea    = (const float*)d_in[3];
    const int*   batch = (const int*)d_in[4];
    const float* Wconv = (const float*)d_in[5];
    const float* Wedge = (const float*)d_in[6];
    // d_in[7] = D_bloom: dead (bloom_pos never reaches an output)
    const float* Wg    = (const float*)d_in[8];
    // d_in[9] = W_gattr: contribution cancels exactly within each cluster

    float*  out = (float*)d_out;
    uint_t* ws  = (uint_t*)d_ws;

    if (ws_size < (size_t)WS_WORDS * 4) return;

    ushort_t* m1b    = (ushort_t*)(ws + W_M1B);
    uint_t*   offs   = ws + W_OFFS;
    float*    newpos = (float*)(ws + W_NEWPOS);
    ushort_t* aggb   = (ushort_t*)(ws + W_AGGB);
    uint_t*   sedge  = ws + W_SSRC;
    uint_t*   pkA    = ws + W_PKA;
    uint_t*   pkC    = ws + W_PKC;
    uint_t*   bhA    = ws + W_BHA;
    uint_t*   bhC    = ws + W_BHC;
    uint_t*   bbA    = ws + W_BBA;
    uint_t*   bbC    = ws + W_BBC;
    uint_t*   bcurA  = ws + W_BCURA;
    uint_t*   bcurC  = ws + W_BCURC;
    uint_t*   bcntC  = ws + W_BCNTC;
    uint_t*   ebase  = ws + W_EBASE;
    uint_t*   xb     = (uint_t*)(out + O_EI);   // 6.4M-word bf16-x staging in out region

    hipMemsetAsync(bhA, 0, (size_t)(2 * NBKT) * 4, stream);   // bhA + bhC contiguous

    xpack<<<dim3(12500), dim3(256), 0, stream>>>((const float4*)x, (uint2*)xb);
    build_m1f<<<dim3(131), dim3(128), 0, stream>>>(Wconv, Wedge, Wg, m1b);
    edge_hist<<<dim3(256), dim3(256), 0, stream>>>(ei, bhA, bhC);
    scan_small<<<dim3(1), dim3(256), 0, stream>>>(bhA, bbA, bcurA, NBKT);
    scan_small<<<dim3(1), dim3(256), 0, stream>>>(bhC, bbC, bcurC, NBKT);
    bucket_place_A<<<dim3((EE + TPB - 1) / TPB), dim3(256), 0, stream>>>(ei, bcurA, pkA);
    bucket_place_C<<<dim3((EE + TPB - 1) / TPB), dim3(256), 0, stream>>>(ei, bcurC, pkC);
    bucket_sort_A<<<dim3(NBKT), dim3(256), 0, stream>>>(bbA, pkA, sedge, offs);
    cluster_pass<<<dim3(98), dim3(256), 0, stream>>>(pos, batch, newpos, out);
    cluster_reduce<<<dim3(6250), dim3(256), 0, stream>>>(offs, sedge, ei, ea, xb, aggb);
    gemm_tiled<<<dim3((CC + GEMM_CPB - 1) / GEMM_CPB), dim3(256), 0, stream>>>(aggb, m1b, out);
    // x_bf16 staging no longer needed: zero the EI/ATTR region (incl. padding tail)
    hipMemsetAsync((char*)d_out + (size_t)O_EI * 4, 0, (size_t)(3200000 + 4800000) * 4, stream);
    enc_count<<<dim3(NBKT * 8), dim3(256), 0, stream>>>(bbC, pkC, bcntC);
    scan_small<<<dim3(1), dim3(256), 0, stream>>>(bcntC, ebase, (uint_t*)0, NBKT * 8);
    enc_emit<<<dim3(NBKT * 8), dim3(256), 0, stream>>>(bbC, pkC, ebase, newpos, out);
}